// Round 8
// baseline (158.524 us; speedup 1.0000x reference)
//
#include <hip/hip_runtime.h>
#include <hip/hip_bf16.h>

// DialogueGCN on MI355X — fp32 in/out; bf16 MFMA everywhere, fp32 banded
// softmax. Off-band attn <= e^-64 -> dropped (row max >= ||x_i||^2 ~ 128);
// softmax Z still counts the (N-band) off-band zeros.
// R8: de-latency the last two 1-wave-ish phases. head: 4 waves/block split
// the E N-tiles (R7 head was 64-thr blocks -> ~80 serial L2 frag loads, 1.5
// waves/CU). prep attn: 384 blocks. layer: 16-col slices, grid (8,192) =
// 6 blocks/CU (same MFMA count + same L2 traffic, 2x concurrency).
// Harness floor context: two 256MiB 0xAA ws-poison fills (~43us each, 75-82%
// HBM peak) + d_in restores + ~7 dispatch boundaries are outside our control.

#define NN   6144
#define DD   128
#define WINW 10
#define YST  88    // Ys row stride (u16): 80 cols + 8 pad

typedef unsigned short u16;
typedef __attribute__((ext_vector_type(8))) short bf16x8;  // MFMA A/B frag
typedef __attribute__((ext_vector_type(4))) float f32x4;   // MFMA C/D frag

__device__ __forceinline__ float b2f(u16 u) {
    return __uint_as_float(((unsigned int)u) << 16);
}
__device__ __forceinline__ u16 f2b(float f) {
    __hip_bfloat16 h = __float2bfloat16(f);   // RNE
    return *reinterpret_cast<u16*>(&h);
}
__device__ __forceinline__ bf16x8 cvt8(const float* p) {
    float4 u = *reinterpret_cast<const float4*>(p);
    float4 v = *reinterpret_cast<const float4*>(p + 4);
    bf16x8 r;
    r[0] = (short)f2b(u.x); r[1] = (short)f2b(u.y);
    r[2] = (short)f2b(u.z); r[3] = (short)f2b(u.w);
    r[4] = (short)f2b(v.x); r[5] = (short)f2b(v.y);
    r[6] = (short)f2b(v.z); r[7] = (short)f2b(v.w);
    return r;
}

// ---------------- prep: blocks [0,64) pack bf16 B^T weights; [64,448) attn --
__global__ __launch_bounds__(256) void prep_kernel(
    const float* __restrict__ x,
    const float* __restrict__ p0, const float* __restrict__ p1,
    const float* __restrict__ p2, const float* __restrict__ p3,
    const float* __restrict__ p4,
    const float* __restrict__ q0, const float* __restrict__ q1,
    const float* __restrict__ q2, const float* __restrict__ q3,
    const float* __restrict__ q4,
    const float* __restrict__ we1, const float* __restrict__ we2,
    const float* __restrict__ ws,
    u16* __restrict__ W1T, u16* __restrict__ W2T, u16* __restrict__ We1T,
    u16* __restrict__ we2T, u16* __restrict__ wsT,
    float* __restrict__ bandw)
{
    const int tid = threadIdx.x;

    if (blockIdx.x < 64) {
        int t = blockIdx.x * 256 + tid;              // 0..16383
        const float* Ws1[5] = {p0, p1, p2, p3, p4};
        const float* Ws2[5] = {q0, q1, q2, q3, q4};
        #pragma unroll
        for (int r = 0; r < 5; ++r) {
            int idx = t + r * 16384;                 // W*T[n][k] = W[k][n&127]
            int k = idx & 127, c = (idx >> 7) & 127;
            W1T[idx] = f2b(Ws1[r][k * 128 + c]);
            W2T[idx] = f2b(Ws2[r][k * 128 + c]);
        }
        #pragma unroll
        for (int r = 0; r < 2; ++r) {
            int idx = t + r * 16384;                 // We1T[n][k] (128x256)
            int n = idx >> 8, k = idx & 255;
            We1T[idx] = f2b(we1[k * 128 + n]);
        }
        if (blockIdx.x == 0) {
            #pragma unroll
            for (int r = 0; r < 8; ++r) {            // we2T: 16x128, pad n>=7
                int idx = tid + r * 256;
                int n = idx >> 7, k = idx & 127;
                we2T[idx] = f2b(n < 7 ? we2[k * 7 + n] : 0.f);
            }
            #pragma unroll
            for (int r = 0; r < 16; ++r) {           // wsT: 16x256, pad n>=7
                int idx = tid + r * 256;
                int n = idx >> 8, k = idx & 255;
                wsT[idx] = f2b(n < 7 ? ws[k * 7 + n] : 0.f);
            }
        }
        return;
    }

    __shared__ float Xs[36][132];
    __shared__ float Ss[16][24];
    const int r0 = (blockIdx.x - 64) * 16;           // 384 attn blocks

    #pragma unroll
    for (int it = 0; it < 5; ++it) {                 // stage 36 rows (clamped)
        int f = tid + it * 256;
        if (f < 36 * 32) {
            int s = f >> 5, c = f & 31;
            int g = r0 - WINW + s;
            if (g >= 0 && g < NN)
                *reinterpret_cast<float4*>(&Xs[s][c * 4]) =
                    *reinterpret_cast<const float4*>(&x[(size_t)g * DD + c * 4]);
        }
    }
    __syncthreads();

    #pragma unroll
    for (int r = 0; r < 2; ++r) {                    // thread-per-(row,offset)
        int p = tid + r * 256;
        if (p >= 336) break;                         // 16*21
        int il = p / 21, o = p - il * 21;
        int jg = r0 + il - WINW + o;
        float sv = -1e30f;
        if (jg >= 0 && jg < NN) {
            const float* xr = &Xs[il + WINW][0];
            const float* jr = &Xs[il + o][0];
            float a0 = 0.f, a1 = 0.f, a2 = 0.f, a3 = 0.f;
            #pragma unroll 8
            for (int k4 = 0; k4 < 32; ++k4) {
                float4 a = *reinterpret_cast<const float4*>(xr + k4 * 4);
                float4 b = *reinterpret_cast<const float4*>(jr + k4 * 4);
                a0 = fmaf(a.x, b.x, a0); a1 = fmaf(a.y, b.y, a1);
                a2 = fmaf(a.z, b.z, a2); a3 = fmaf(a.w, b.w, a3);
            }
            sv = (a0 + a1) + (a2 + a3);
        }
        Ss[il][o] = sv;
    }
    __syncthreads();

    if (tid < 16) {                                  // finalize softmax rows
        int il = tid, i = r0 + il;
        float m = 0.f;
        #pragma unroll
        for (int o = 0; o < 21; ++o) {
            float s = Ss[il][o];
            if (s > -1e29f) m = fmaxf(m, s);
        }
        int lo = i - WINW; if (lo < 0) lo = 0;
        int hi = i + WINW; if (hi > NN - 1) hi = NN - 1;
        float Z = (float)(NN - (hi - lo + 1)) * expf(-m);
        float ev[21];
        #pragma unroll
        for (int o = 0; o < 21; ++o) {
            float s = Ss[il][o];
            ev[o] = (s > -1e29f) ? expf(s - m) : 0.f;
            Z += ev[o];
        }
        #pragma unroll
        for (int o = 0; o < 21; ++o) bandw[i * 32 + o] = ev[o] / Z;
    }
}

// ---------------- fused layer: MFMA Y-tile (LDS) + table-driven combine -----
// Block (hb, by): rows [by*32, by*32+32) of h, cols [hb*16, hb*16+16).
// Wave w = M-tile w of the 64-row (incl halo+pad) x 80-col Y tile.
__global__ __launch_bounds__(256) void layer_kernel(
    const float* __restrict__ Af, const u16* __restrict__ Ab16,
    const u16* __restrict__ BT, const float* __restrict__ bandw,
    const int* __restrict__ spk, u16* __restrict__ hout, int a_is_f32)
{
    __shared__ u16 Ys[52][YST];
    __shared__ int2 tab[32 * 22];                    // {w bits, u16 offset}
    const int tid  = threadIdx.x;
    const int wave = tid >> 6, lane = tid & 63;
    const int lm = lane & 15, quad = lane >> 4;
    const int bm = blockIdx.y * 32;
    const int hb = blockIdx.x;                       // 0..7, 16-col slice

    // Phase 0: pre-resolve combine coefficients/offsets
    for (int p = tid; p < 704; p += 256) {
        int il = p / 22, e = p - il * 22;
        int i  = bm + il;
        int si = spk[i];
        float w; int off;
        if (e < 21) {
            int j = i - WINW + e;
            bool valid = (j >= 0) && (j < NN);
            int jc  = valid ? j : i;
            int sel = (spk[jc] == si) ? ((j >= i) ? 0 : 1) : ((j >= i) ? 2 : 3);
            w   = valid ? bandw[(size_t)i * 32 + e] : 0.f;
            off = valid ? (il + e) * YST + sel * 16 : 0;   // Ys[0][0] is written
        } else {                                     // aggr * diag term
            w   = bandw[(size_t)i * 32 + WINW];
            off = (il + WINW) * YST + 4 * 16;
        }
        tab[p] = make_int2(__float_as_int(w), off);
    }

    // Phase 1: MFMA 64(M incl halo+pad) x 80(N) Y-tile into LDS
    int gr = bm - WINW + wave * 16 + lm;
    gr = min(max(gr, 0), NN - 1);                    // clamp halo/pad rows
    bf16x8 afr[4];
    #pragma unroll
    for (int s = 0; s < 4; ++s) {
        if (a_is_f32)
            afr[s] = cvt8(Af + (size_t)gr * DD + s * 32 + quad * 8);
        else
            afr[s] = *reinterpret_cast<const bf16x8*>(
                Ab16 + (size_t)gr * DD + s * 32 + quad * 8);
    }

    f32x4 acc[5];
    #pragma unroll
    for (int n = 0; n < 5; ++n) acc[n] = {0.f, 0.f, 0.f, 0.f};

    #pragma unroll
    for (int nt = 0; nt < 5; ++nt) {                 // nt == sel
        int gn = nt * 128 + hb * 16 + lm;
        #pragma unroll
        for (int s = 0; s < 4; ++s) {
            bf16x8 b = *reinterpret_cast<const bf16x8*>(
                BT + (size_t)gn * DD + s * 32 + quad * 8);
            acc[nt] = __builtin_amdgcn_mfma_f32_16x16x32_bf16(afr[s], b, acc[nt], 0, 0, 0);
        }
    }
    // C/D: col = lane&15, row = quad*4 + reg
    #pragma unroll
    for (int nt = 0; nt < 5; ++nt)
        #pragma unroll
        for (int r = 0; r < 4; ++r) {
            int lr = wave * 16 + quad * 4 + r;
            if (lr < 52) Ys[lr][nt * 16 + lm] = f2b(acc[nt][r]);
        }
    __syncthreads();

    // Phase 2: combine — 32 rows x 8 col-pairs, LDS-only
    const int c0 = (tid & 7) * 2;
    const int il = tid >> 3;
    float a0 = 0.f, a1 = 0.f;
    const int2* tp = &tab[il * 22];
    #pragma unroll
    for (int e = 0; e < 22; ++e) {
        int2 t = tp[e];
        float w = __int_as_float(t.x);
        unsigned y2 = *reinterpret_cast<const unsigned*>(&Ys[0][0] + t.y + c0);
        a0 = fmaf(w, b2f((u16)(y2 & 0xffff)), a0);
        a1 = fmaf(w, b2f((u16)(y2 >> 16)), a1);
    }
    int i = bm + il;
    unsigned pk = ((unsigned)f2b(fmaxf(a1, 0.f)) << 16) | f2b(fmaxf(a0, 0.f));
    *reinterpret_cast<unsigned*>(&hout[(size_t)i * DD + hb * 16 + c0]) = pk;
}

// ---------------- head: E = relu([h2|x]@w_e1+b_e1); emo = E@we2; sentiment --
// 384 blocks x 256 thr; all 4 waves cover the same 16 rows, splitting the 8
// E N-tiles (2 each); wave 3 also does the sentiment tile; wave 0 does the
// emotion pass over the LDS E-tile after the barrier.
__global__ __launch_bounds__(256) void head_kernel(
    const u16* __restrict__ h2b, const float* __restrict__ x,
    const u16* __restrict__ We1T, const float* __restrict__ be1,
    const u16* __restrict__ we2T, const float* __restrict__ be2,
    const u16* __restrict__ wsT,  const float* __restrict__ bs,
    float* __restrict__ out)
{
    __shared__ float Es[16][132];
    const int tid  = threadIdx.x;
    const int wave = tid >> 6, lane = tid & 63;
    const int lm = lane & 15, quad = lane >> 4;
    const int bm = blockIdx.x * 16;
    const int row = bm + lm;

    bf16x8 afr[8];                                   // K=256: h2 then x
    #pragma unroll
    for (int s = 0; s < 4; ++s)
        afr[s] = *reinterpret_cast<const bf16x8*>(
            &h2b[(size_t)row * DD + s * 32 + quad * 8]);
    #pragma unroll
    for (int s = 4; s < 8; ++s)
        afr[s] = cvt8(&x[(size_t)row * DD + (s - 4) * 32 + quad * 8]);

    f32x4 accE[2], accS = {0.f, 0.f, 0.f, 0.f};
    accE[0] = {0.f, 0.f, 0.f, 0.f};
    accE[1] = {0.f, 0.f, 0.f, 0.f};

    #pragma unroll
    for (int s = 0; s < 8; ++s) {
        #pragma unroll
        for (int t = 0; t < 2; ++t) {
            int nt = wave * 2 + t;
            bf16x8 b = *reinterpret_cast<const bf16x8*>(
                &We1T[(size_t)(nt * 16 + lm) * 256 + s * 32 + quad * 8]);
            accE[t] = __builtin_amdgcn_mfma_f32_16x16x32_bf16(afr[s], b, accE[t], 0, 0, 0);
        }
        if (wave == 3) {
            bf16x8 bsf = *reinterpret_cast<const bf16x8*>(
                &wsT[(size_t)lm * 256 + s * 32 + quad * 8]);
            accS = __builtin_amdgcn_mfma_f32_16x16x32_bf16(afr[s], bsf, accS, 0, 0, 0);
        }
    }

    if (wave == 3 && lm < 7) {                       // sentiment epilogue
        #pragma unroll
        for (int r = 0; r < 4; ++r) {
            int i = bm + quad * 4 + r;
            out[(size_t)NN * 7 + (size_t)i * 7 + lm] = accS[r] + bs[lm];
        }
    }
    #pragma unroll
    for (int t = 0; t < 2; ++t) {                    // E tile -> LDS (bias+relu)
        int col = (wave * 2 + t) * 16 + lm;
        float bias = be1[col];
        #pragma unroll
        for (int r = 0; r < 4; ++r)
            Es[quad * 4 + r][col] = fmaxf(accE[t][r] + bias, 0.f);
    }
    __syncthreads();

    if (wave == 0) {                                 // emotion: E @ we2
        f32x4 accM = {0.f, 0.f, 0.f, 0.f};
        #pragma unroll
        for (int s = 0; s < 4; ++s) {
            bf16x8 a = cvt8(&Es[lm][s * 32 + quad * 8]);
            bf16x8 b = *reinterpret_cast<const bf16x8*>(
                &we2T[(size_t)lm * 128 + s * 32 + quad * 8]);
            accM = __builtin_amdgcn_mfma_f32_16x16x32_bf16(a, b, accM, 0, 0, 0);
        }
        if (lm < 7) {
            #pragma unroll
            for (int r = 0; r < 4; ++r) {
                int i = bm + quad * 4 + r;
                out[(size_t)i * 7 + lm] = accM[r] + be2[lm];
            }
        }
    }
}

extern "C" void kernel_launch(void* const* d_in, const int* in_sizes, int n_in,
                              void* d_out, int out_size, void* d_ws, size_t ws_size,
                              hipStream_t stream)
{
    const float* x   = (const float*)d_in[0];
    const int*   spk = (const int*)d_in[1];
    const float* Wp1 = (const float*)d_in[2];
    const float* Wu1 = (const float*)d_in[3];
    const float* Wm1 = (const float*)d_in[4];
    const float* Wd1 = (const float*)d_in[5];
    const float* Wp2 = (const float*)d_in[6];
    const float* Wu2 = (const float*)d_in[7];
    const float* Wm2 = (const float*)d_in[8];
    const float* Wd2 = (const float*)d_in[9];
    const float* wa1 = (const float*)d_in[10];
    const float* wa2 = (const float*)d_in[11];
    const float* we1 = (const float*)d_in[12];
    const float* be1 = (const float*)d_in[13];
    const float* we2 = (const float*)d_in[14];
    const float* be2 = (const float*)d_in[15];
    const float* wss = (const float*)d_in[16];
    const float* bss = (const float*)d_in[17];

    // workspace layout (bytes; 16B-aligned), total ~4.3 MB
    char* base = (char*)d_ws;
    float* bandw = (float*)(base);                 //   786,432 B
    u16*   W1T   = (u16*)(base + 786432);          //   163,840 B
    u16*   W2T   = (u16*)(base + 950272);          //   163,840 B
    u16*   We1T  = (u16*)(base + 1114112);         //    65,536 B
    u16*   we2T  = (u16*)(base + 1179648);         //     4,096 B
    u16*   wsT   = (u16*)(base + 1183744);         //     8,192 B
    u16*   h1b   = (u16*)(base + 1191936);         // 1,572,864 B
    u16*   h2b   = (u16*)(base + 2764800);         // 1,572,864 B

    prep_kernel<<<448, 256, 0, stream>>>(x, Wp1, Wu1, Wm1, Wd1, wa1,
                                         Wp2, Wu2, Wm2, Wd2, wa2,
                                         we1, we2, wss,
                                         W1T, W2T, We1T, we2T, wsT, bandw);
    layer_kernel<<<dim3(8, 192), 256, 0, stream>>>(x, nullptr, W1T, bandw, spk, h1b, 1);
    layer_kernel<<<dim3(8, 192), 256, 0, stream>>>(nullptr, h1b, W2T, bandw, spk, h2b, 0);
    head_kernel<<<384, 256, 0, stream>>>(h2b, x, We1T, be1, we2T, be2, wsT, bss,
                                         (float*)d_out);
}

// Round 9
// 139.509 us; speedup vs baseline: 1.1363x; 1.1363x over previous
//
#include <hip/hip_runtime.h>
#include <hip/hip_bf16.h>

// DialogueGCN on MI355X — fp32 in/out; bf16 MFMA everywhere, fp32 banded
// softmax. Off-band attn <= e^-64 -> dropped (row max >= ||x_i||^2 ~ 128);
// softmax Z still counts the (N-band) off-band zeros.
// R9 = exact revert to R7 (best measured: 139.0us). R8's 3-way restructure
// (smaller attn blocks / 16-col layer slices / 256-thr head) regressed to
// 158.5us with no counter-visible culprit (all our kernels < the 41us
// harness poison fills). This run re-establishes the baseline and probes
// run-to-run noise; if ~139 reproduces, remaining headroom (~10-15us of
// sub-visibility kernel time over a ~125us harness floor) ends the session.
// R7 provenance: layer kernel de-latency-fied vs R6 (54us, all pipes idle):
// pre-resolved (w, offset) int2 tables in LDS (combine = ds_read_b64 +
// ds_read_b32 + 2 fma, no global traffic, no branches); 32-col slices,
// grid (4,192) = 768 blocks = 3 blocks/CU.

#define NN   6144
#define DD   128
#define WINW 10
#define YST  168   // Ys row stride (u16): 160 cols + 8 pad

typedef unsigned short u16;
typedef __attribute__((ext_vector_type(8))) short bf16x8;  // MFMA A/B frag
typedef __attribute__((ext_vector_type(4))) float f32x4;   // MFMA C/D frag

__device__ __forceinline__ float b2f(u16 u) {
    return __uint_as_float(((unsigned int)u) << 16);
}
__device__ __forceinline__ u16 f2b(float f) {
    __hip_bfloat16 h = __float2bfloat16(f);   // RNE
    return *reinterpret_cast<u16*>(&h);
}
__device__ __forceinline__ bf16x8 cvt8(const float* p) {
    float4 u = *reinterpret_cast<const float4*>(p);
    float4 v = *reinterpret_cast<const float4*>(p + 4);
    bf16x8 r;
    r[0] = (short)f2b(u.x); r[1] = (short)f2b(u.y);
    r[2] = (short)f2b(u.z); r[3] = (short)f2b(u.w);
    r[4] = (short)f2b(v.x); r[5] = (short)f2b(v.y);
    r[6] = (short)f2b(v.z); r[7] = (short)f2b(v.w);
    return r;
}

// ---------------- prep: blocks [0,64) pack bf16 B^T weights; [64,256) attn --
__global__ __launch_bounds__(256) void prep_kernel(
    const float* __restrict__ x,
    const float* __restrict__ p0, const float* __restrict__ p1,
    const float* __restrict__ p2, const float* __restrict__ p3,
    const float* __restrict__ p4,
    const float* __restrict__ q0, const float* __restrict__ q1,
    const float* __restrict__ q2, const float* __restrict__ q3,
    const float* __restrict__ q4,
    const float* __restrict__ we1, const float* __restrict__ we2,
    const float* __restrict__ ws,
    u16* __restrict__ W1T, u16* __restrict__ W2T, u16* __restrict__ We1T,
    u16* __restrict__ we2T, u16* __restrict__ wsT,
    float* __restrict__ bandw)
{
    const int tid = threadIdx.x;

    if (blockIdx.x < 64) {
        int t = blockIdx.x * 256 + tid;              // 0..16383
        const float* Ws1[5] = {p0, p1, p2, p3, p4};
        const float* Ws2[5] = {q0, q1, q2, q3, q4};
        #pragma unroll
        for (int r = 0; r < 5; ++r) {
            int idx = t + r * 16384;                 // W*T[n][k] = W[k][n&127]
            int k = idx & 127, c = (idx >> 7) & 127;
            W1T[idx] = f2b(Ws1[r][k * 128 + c]);
            W2T[idx] = f2b(Ws2[r][k * 128 + c]);
        }
        #pragma unroll
        for (int r = 0; r < 2; ++r) {
            int idx = t + r * 16384;                 // We1T[n][k] (128x256)
            int n = idx >> 8, k = idx & 255;
            We1T[idx] = f2b(we1[k * 128 + n]);
        }
        if (blockIdx.x == 0) {
            #pragma unroll
            for (int r = 0; r < 8; ++r) {            // we2T: 16x128, pad n>=7
                int idx = tid + r * 256;
                int n = idx >> 7, k = idx & 127;
                we2T[idx] = f2b(n < 7 ? we2[k * 7 + n] : 0.f);
            }
            #pragma unroll
            for (int r = 0; r < 16; ++r) {           // wsT: 16x256, pad n>=7
                int idx = tid + r * 256;
                int n = idx >> 8, k = idx & 255;
                wsT[idx] = f2b(n < 7 ? ws[k * 7 + n] : 0.f);
            }
        }
        return;
    }

    __shared__ float Xs[52][132];
    __shared__ float Ss[32][24];
    const int r0 = (blockIdx.x - 64) * 32;           // 192 attn blocks

    #pragma unroll
    for (int it = 0; it < 7; ++it) {
        int f = tid + it * 256;
        if (f < 52 * 32) {
            int s = f >> 5, c = f & 31;
            int g = r0 - WINW + s;
            if (g >= 0 && g < NN)
                *reinterpret_cast<float4*>(&Xs[s][c * 4]) =
                    *reinterpret_cast<const float4*>(&x[(size_t)g * DD + c * 4]);
        }
    }
    __syncthreads();

    #pragma unroll
    for (int r = 0; r < 3; ++r) {                    // thread-per-(row,offset)
        int p = tid + r * 256;
        if (p >= 672) break;
        int il = p / 21, o = p - il * 21;
        int jg = r0 + il - WINW + o;
        float sv = -1e30f;
        if (jg >= 0 && jg < NN) {
            const float* xr = &Xs[il + WINW][0];
            const float* jr = &Xs[il + o][0];
            float a0 = 0.f, a1 = 0.f, a2 = 0.f, a3 = 0.f;
            #pragma unroll 8
            for (int k4 = 0; k4 < 32; ++k4) {
                float4 a = *reinterpret_cast<const float4*>(xr + k4 * 4);
                float4 b = *reinterpret_cast<const float4*>(jr + k4 * 4);
                a0 = fmaf(a.x, b.x, a0); a1 = fmaf(a.y, b.y, a1);
                a2 = fmaf(a.z, b.z, a2); a3 = fmaf(a.w, b.w, a3);
            }
            sv = (a0 + a1) + (a2 + a3);
        }
        Ss[il][o] = sv;
    }
    __syncthreads();

    if (tid < 32) {                                  // finalize softmax rows
        int il = tid, i = r0 + il;
        float m = 0.f;
        #pragma unroll
        for (int o = 0; o < 21; ++o) {
            float s = Ss[il][o];
            if (s > -1e29f) m = fmaxf(m, s);
        }
        int lo = i - WINW; if (lo < 0) lo = 0;
        int hi = i + WINW; if (hi > NN - 1) hi = NN - 1;
        float Z = (float)(NN - (hi - lo + 1)) * expf(-m);
        float ev[21];
        #pragma unroll
        for (int o = 0; o < 21; ++o) {
            float s = Ss[il][o];
            ev[o] = (s > -1e29f) ? expf(s - m) : 0.f;
            Z += ev[o];
        }
        #pragma unroll
        for (int o = 0; o < 21; ++o) bandw[i * 32 + o] = ev[o] / Z;
    }
}

// ---------------- fused layer: MFMA Y-tile (LDS) + table-driven combine -----
// Block (hb, by): rows [by*32, by*32+32) of h, cols [hb*32, hb*32+32).
// Phase 0: build 32x22 (w, Ys-offset) pairs in LDS (all global reads here).
// Phase 1: Y rows [by*32-10, by*32+42) (pad 64) x {sel*128+hb*32+[0,32)} for
// sel 0..4 -> bf16 LDS tile. Phase 2: combine = pure LDS reads + fma.
__global__ __launch_bounds__(256) void layer_kernel(
    const float* __restrict__ Af, const u16* __restrict__ Ab16,
    const u16* __restrict__ BT, const float* __restrict__ bandw,
    const int* __restrict__ spk, u16* __restrict__ hout, int a_is_f32)
{
    __shared__ u16 Ys[52][YST];
    __shared__ int2 tab[32 * 22];                    // {w bits, u16 offset}
    const int tid  = threadIdx.x;
    const int wave = tid >> 6, lane = tid & 63;
    const int lm = lane & 15, quad = lane >> 4;
    const int wm = wave >> 1, wn = wave & 1;         // 2x2 wave grid
    const int bm = blockIdx.y * 32;
    const int hb = blockIdx.x;                       // 0..3, 32-col slice

    // Phase 0: pre-resolve combine coefficients/offsets (overlaps phase 1)
    for (int p = tid; p < 704; p += 256) {
        int il = p / 22, e = p - il * 22;
        int i  = bm + il;
        int si = spk[i];
        float w; int off;
        if (e < 21) {
            int j = i - WINW + e;
            bool valid = (j >= 0) && (j < NN);
            int jc  = valid ? j : i;
            int sel = (spk[jc] == si) ? ((j >= i) ? 0 : 1) : ((j >= i) ? 2 : 3);
            w   = valid ? bandw[(size_t)i * 32 + e] : 0.f;
            off = valid ? (il + e) * YST + sel * 32 : 0;   // Ys[0][0] is written
        } else {                                     // aggr * diag term
            w   = bandw[(size_t)i * 32 + WINW];
            off = (il + WINW) * YST + 4 * 32;
        }
        tab[p] = make_int2(__float_as_int(w), off);
    }

    // Phase 1: MFMA the 64(M incl halo+pad) x 160(N) Y-tile into LDS
    bf16x8 afr[2][4];
    #pragma unroll
    for (int mt = 0; mt < 2; ++mt) {
        int gr = bm - WINW + (wm * 2 + mt) * 16 + lm;
        gr = min(max(gr, 0), NN - 1);                // clamp halo/pad rows
        #pragma unroll
        for (int s = 0; s < 4; ++s) {
            if (a_is_f32)
                afr[mt][s] = cvt8(Af + (size_t)gr * DD + s * 32 + quad * 8);
            else
                afr[mt][s] = *reinterpret_cast<const bf16x8*>(
                    Ab16 + (size_t)gr * DD + s * 32 + quad * 8);
        }
    }

    f32x4 acc[2][5];
    #pragma unroll
    for (int mt = 0; mt < 2; ++mt)
        #pragma unroll
        for (int n = 0; n < 5; ++n) acc[mt][n] = {0.f, 0.f, 0.f, 0.f};

    #pragma unroll
    for (int np = 0; np < 5; ++np) {
        int nt = wn * 5 + np;                        // 10 N-tiles of 16
        int gn = (nt >> 1) * 128 + hb * 32 + (nt & 1) * 16 + lm;
        #pragma unroll
        for (int s = 0; s < 4; ++s) {
            bf16x8 b = *reinterpret_cast<const bf16x8*>(
                BT + (size_t)gn * DD + s * 32 + quad * 8);
            acc[0][np] = __builtin_amdgcn_mfma_f32_16x16x32_bf16(afr[0][s], b, acc[0][np], 0, 0, 0);
            acc[1][np] = __builtin_amdgcn_mfma_f32_16x16x32_bf16(afr[1][s], b, acc[1][np], 0, 0, 0);
        }
    }
    // C/D: col = lane&15, row = quad*4 + reg
    #pragma unroll
    for (int mt = 0; mt < 2; ++mt)
        #pragma unroll
        for (int np = 0; np < 5; ++np) {
            int nt = wn * 5 + np;
            #pragma unroll
            for (int r = 0; r < 4; ++r) {
                int lr = (wm * 2 + mt) * 16 + quad * 4 + r;
                if (lr < 52) Ys[lr][nt * 16 + lm] = f2b(acc[mt][np][r]);
            }
        }
    __syncthreads();

    // Phase 2: combine — 16 row-groups x (16 threads x 2 cols), LDS-only
    const int c0 = (tid & 15) * 2;
    const int rg = tid >> 4;
    #pragma unroll
    for (int rr = 0; rr < 2; ++rr) {
        int il = rg * 2 + rr;
        float a0 = 0.f, a1 = 0.f;
        const int2* tp = &tab[il * 22];
        #pragma unroll
        for (int e = 0; e < 22; ++e) {
            int2 t = tp[e];
            float w = __int_as_float(t.x);
            unsigned y2 = *reinterpret_cast<const unsigned*>(
                &Ys[0][0] + t.y + c0);
            a0 = fmaf(w, b2f((u16)(y2 & 0xffff)), a0);
            a1 = fmaf(w, b2f((u16)(y2 >> 16)), a1);
        }
        int i = bm + il;
        unsigned pk = ((unsigned)f2b(fmaxf(a1, 0.f)) << 16) | f2b(fmaxf(a0, 0.f));
        *reinterpret_cast<unsigned*>(&hout[(size_t)i * DD + hb * 32 + c0]) = pk;
    }
}

// ---------------- head: E = relu([h2|x]@w_e1+b_e1); emo = E@we2; sentiment --
__global__ __launch_bounds__(64) void head_kernel(
    const u16* __restrict__ h2b, const float* __restrict__ x,
    const u16* __restrict__ We1T, const float* __restrict__ be1,
    const u16* __restrict__ we2T, const float* __restrict__ be2,
    const u16* __restrict__ wsT,  const float* __restrict__ bs,
    float* __restrict__ out)
{
    __shared__ float Es[16][132];
    const int lane = threadIdx.x;
    const int lm = lane & 15, quad = lane >> 4;
    const int bm = blockIdx.x * 16;
    const int row = bm + lm;

    bf16x8 afr[8];                                   // K=256: h2 then x
    #pragma unroll
    for (int s = 0; s < 4; ++s)
        afr[s] = *reinterpret_cast<const bf16x8*>(
            &h2b[(size_t)row * DD + s * 32 + quad * 8]);
    #pragma unroll
    for (int s = 4; s < 8; ++s)
        afr[s] = cvt8(&x[(size_t)row * DD + (s - 4) * 32 + quad * 8]);

    f32x4 accE[8], accS = {0.f, 0.f, 0.f, 0.f};
    #pragma unroll
    for (int nt = 0; nt < 8; ++nt) accE[nt] = {0.f, 0.f, 0.f, 0.f};

    #pragma unroll
    for (int s = 0; s < 8; ++s) {
        #pragma unroll
        for (int nt = 0; nt < 8; ++nt) {
            bf16x8 b = *reinterpret_cast<const bf16x8*>(
                &We1T[(size_t)(nt * 16 + lm) * 256 + s * 32 + quad * 8]);
            accE[nt] = __builtin_amdgcn_mfma_f32_16x16x32_bf16(afr[s], b, accE[nt], 0, 0, 0);
        }
        bf16x8 bsf = *reinterpret_cast<const bf16x8*>(
            &wsT[(size_t)lm * 256 + s * 32 + quad * 8]);
        accS = __builtin_amdgcn_mfma_f32_16x16x32_bf16(afr[s], bsf, accS, 0, 0, 0);
    }

    if (lm < 7) {                                    // sentiment epilogue
        #pragma unroll
        for (int r = 0; r < 4; ++r) {
            int i = bm + quad * 4 + r;
            out[(size_t)NN * 7 + (size_t)i * 7 + lm] = accS[r] + bs[lm];
        }
    }
    #pragma unroll
    for (int nt = 0; nt < 8; ++nt) {                 // E tile -> LDS (bias+relu)
        int col = nt * 16 + lm;
        float bias = be1[col];
        #pragma unroll
        for (int r = 0; r < 4; ++r)
            Es[quad * 4 + r][col] = fmaxf(accE[nt][r] + bias, 0.f);
    }
    __syncthreads();

    f32x4 accM = {0.f, 0.f, 0.f, 0.f};               // emotion: E @ we2
    #pragma unroll
    for (int s = 0; s < 4; ++s) {
        bf16x8 a = cvt8(&Es[lm][s * 32 + quad * 8]);
        bf16x8 b = *reinterpret_cast<const bf16x8*>(
            &we2T[(size_t)lm * 128 + s * 32 + quad * 8]);
        accM = __builtin_amdgcn_mfma_f32_16x16x32_bf16(a, b, accM, 0, 0, 0);
    }
    if (lm < 7) {
        #pragma unroll
        for (int r = 0; r < 4; ++r) {
            int i = bm + quad * 4 + r;
            out[(size_t)i * 7 + lm] = accM[r] + be2[lm];
        }
    }
}

extern "C" void kernel_launch(void* const* d_in, const int* in_sizes, int n_in,
                              void* d_out, int out_size, void* d_ws, size_t ws_size,
                              hipStream_t stream)
{
    const float* x   = (const float*)d_in[0];
    const int*   spk = (const int*)d_in[1];
    const float* Wp1 = (const float*)d_in[2];
    const float* Wu1 = (const float*)d_in[3];
    const float* Wm1 = (const float*)d_in[4];
    const float* Wd1 = (const float*)d_in[5];
    const float* Wp2 = (const float*)d_in[6];
    const float* Wu2 = (const float*)d_in[7];
    const float* Wm2 = (const float*)d_in[8];
    const float* Wd2 = (const float*)d_in[9];
    const float* wa1 = (const float*)d_in[10];
    const float* wa2 = (const float*)d_in[11];
    const float* we1 = (const float*)d_in[12];
    const float* be1 = (const float*)d_in[13];
    const float* we2 = (const float*)d_in[14];
    const float* be2 = (const float*)d_in[15];
    const float* wss = (const float*)d_in[16];
    const float* bss = (const float*)d_in[17];

    // workspace layout (bytes; 16B-aligned), total ~4.3 MB
    char* base = (char*)d_ws;
    float* bandw = (float*)(base);                 //   786,432 B
    u16*   W1T   = (u16*)(base + 786432);          //   163,840 B
    u16*   W2T   = (u16*)(base + 950272);          //   163,840 B
    u16*   We1T  = (u16*)(base + 1114112);         //    65,536 B
    u16*   we2T  = (u16*)(base + 1179648);         //     4,096 B
    u16*   wsT   = (u16*)(base + 1183744);         //     8,192 B
    u16*   h1b   = (u16*)(base + 1191936);         // 1,572,864 B
    u16*   h2b   = (u16*)(base + 2764800);         // 1,572,864 B

    prep_kernel<<<256, 256, 0, stream>>>(x, Wp1, Wu1, Wm1, Wd1, wa1,
                                         Wp2, Wu2, Wm2, Wd2, wa2,
                                         we1, we2, wss,
                                         W1T, W2T, We1T, we2T, wsT, bandw);
    layer_kernel<<<dim3(4, 192), 256, 0, stream>>>(x, nullptr, W1T, bandw, spk, h1b, 1);
    layer_kernel<<<dim3(4, 192), 256, 0, stream>>>(nullptr, h1b, W2T, bandw, spk, h2b, 0);
    head_kernel<<<384, 64, 0, stream>>>(h2b, x, We1T, be1, we2T, be2, wsT, bss,
                                        (float*)d_out);
}